// Round 1
// baseline (32186.365 us; speedup 1.0000x reference)
//
#include <hip/hip_runtime.h>
#include <hip/hip_bf16.h>
#include <math.h>

// Problem dims (fixed by reference)
#define I_DIM 256
#define H_DIM 512
#define B_DIM 64
#define S_DIM 512
#define G4    2048   // 4*H
#define SH    (S_DIM * H_DIM)
#define S1H   ((S_DIM + 1) * H_DIM)

typedef __bf16 bf16_t;
typedef bf16_t bf16x8 __attribute__((ext_vector_type(8)));
typedef float  f32x4  __attribute__((ext_vector_type(4)));

__device__ __forceinline__ float sigm_(float x) { return 1.0f / (1.0f + __expf(-x)); }
__device__ __forceinline__ float softplus_(float x) {
    return (x > 20.0f) ? x : log1pf(__expf(x));
}

// ---------------------------------------------------------------------------
// One-time per call: fp32 -> bf16 weight conversion (+ transpose of G so that
// every MFMA B-operand is K-contiguous: lane needs 8 consecutive k at fixed n).
// W_ih (2048x256) and W_hh (2048x512) are already row-major [n][k]. G (512x1024)
// is [k][n] -> build G_T [n][k] (1024x512).
// ---------------------------------------------------------------------------
__global__ void k_convert(const float* __restrict__ W_ih, const float* __restrict__ W_hh,
                          const float* __restrict__ Gm,
                          bf16_t* __restrict__ W_ih_bf, bf16_t* __restrict__ W_hh_bf,
                          bf16_t* __restrict__ G_T_bf) {
    const int NW_IH = G4 * I_DIM;        // 524288
    const int NW_HH = G4 * H_DIM;        // 1048576
    const int NG    = H_DIM * 2 * H_DIM; // 524288
    int idx = blockIdx.x * blockDim.x + threadIdx.x;
    const int stride = gridDim.x * blockDim.x;
    const int total = NW_IH + NW_HH + NG;
    for (; idx < total; idx += stride) {
        if (idx < NW_IH) {
            W_ih_bf[idx] = (bf16_t)W_ih[idx];
        } else if (idx < NW_IH + NW_HH) {
            int i = idx - NW_IH;
            W_hh_bf[i] = (bf16_t)W_hh[i];
        } else {
            int i = idx - NW_IH - NW_HH;
            int n = i & 1023;       // coalesced read over n
            int k = i >> 10;
            G_T_bf[n * H_DIM + k] = (bf16_t)Gm[k * 1024 + n];
        }
    }
}

// ---------------------------------------------------------------------------
// t=0 sampling: c0 = 0 -> stats = 0 exactly -> mu0 = 1e-6, std0 = ln 2.
// Also zero h0 (bf16) and write c_s0 = mu0 + eps[0]*std0.
// Grid: 128 x 256 = 32768 = B*H exactly.
// ---------------------------------------------------------------------------
__global__ void k_init(const float* __restrict__ eps, bf16_t* __restrict__ h0,
                       float* __restrict__ c_s, float* __restrict__ out_cmu,
                       float* __restrict__ out_cstd) {
    const int i = blockIdx.x * 256 + threadIdx.x;  // b*H + j
    const float std0 = 0.69314718055994530942f;    // softplus(0) = ln 2
    const float mu0  = 1e-6f;
    h0[i] = (bf16_t)0.0f;
    c_s[i] = mu0 + eps[i] * std0;
    const int b = i >> 9, j = i & 511;
    out_cmu [b * S1H + j] = mu0;
    out_cstd[b * S1H + j] = std0;
}

// ---------------------------------------------------------------------------
// Phase A (per step): gates = x_t @ W_ih^T + h_t @ W_hh^T + b; then
// c_new = sig(f)*c_s_prev + sig(i)*tanh(g); h_new = sig(o)*tanh(c_new).
// Grid: 16 wgs x 256 thr. wg w owns cells [w*32, w*32+32). Wave g (0..3)
// computes gate-type g for those cells (W rows g*512 + cell). Cross-gate
// combine via LDS. MFMA 16x16x32 bf16; M=64 (batch), N=32/wave, K=512(+256 x).
// ---------------------------------------------------------------------------
__global__ __launch_bounds__(256) void k_phaseA(
    const bf16_t* __restrict__ h_prev, const float* __restrict__ x,
    const bf16_t* __restrict__ W_hh_bf, const bf16_t* __restrict__ W_ih_bf,
    const float* __restrict__ b_ih, const float* __restrict__ b_hh,
    const float* __restrict__ c_s,
    bf16_t* __restrict__ h_next, bf16_t* __restrict__ c_new_bf,
    float* __restrict__ out_hidden, int t)
{
    __shared__ float lds[4][64][32];   // [gate][batch-row][cell] post-activation

    const int w  = blockIdx.x;        // 0..15 cell-slice
    const int g  = threadIdx.x >> 6;  // wave = gate type
    const int l  = threadIdx.x & 63;
    const int lr = l & 15;
    const int kq = l >> 4;            // 0..3
    const int colbase = g * H_DIM + w * 32;  // column in 2048-wide gate space

    f32x4 acc[4][2];
    #pragma unroll
    for (int m = 0; m < 4; ++m) {
        acc[m][0] = (f32x4){0.f, 0.f, 0.f, 0.f};
        acc[m][1] = (f32x4){0.f, 0.f, 0.f, 0.f};
    }

    // ---- h_t @ W_hh^T : K = 512 ----
    #pragma unroll 4
    for (int kt = 0; kt < 16; ++kt) {
        const int k0 = kt * 32 + kq * 8;
        bf16x8 a0 = *reinterpret_cast<const bf16x8*>(h_prev + (lr +  0) * H_DIM + k0);
        bf16x8 a1 = *reinterpret_cast<const bf16x8*>(h_prev + (lr + 16) * H_DIM + k0);
        bf16x8 a2 = *reinterpret_cast<const bf16x8*>(h_prev + (lr + 32) * H_DIM + k0);
        bf16x8 a3 = *reinterpret_cast<const bf16x8*>(h_prev + (lr + 48) * H_DIM + k0);
        bf16x8 b0 = *reinterpret_cast<const bf16x8*>(W_hh_bf + (size_t)(colbase + lr)      * H_DIM + k0);
        bf16x8 b1 = *reinterpret_cast<const bf16x8*>(W_hh_bf + (size_t)(colbase + 16 + lr) * H_DIM + k0);
        acc[0][0] = __builtin_amdgcn_mfma_f32_16x16x32_bf16(a0, b0, acc[0][0], 0, 0, 0);
        acc[0][1] = __builtin_amdgcn_mfma_f32_16x16x32_bf16(a0, b1, acc[0][1], 0, 0, 0);
        acc[1][0] = __builtin_amdgcn_mfma_f32_16x16x32_bf16(a1, b0, acc[1][0], 0, 0, 0);
        acc[1][1] = __builtin_amdgcn_mfma_f32_16x16x32_bf16(a1, b1, acc[1][1], 0, 0, 0);
        acc[2][0] = __builtin_amdgcn_mfma_f32_16x16x32_bf16(a2, b0, acc[2][0], 0, 0, 0);
        acc[2][1] = __builtin_amdgcn_mfma_f32_16x16x32_bf16(a2, b1, acc[2][1], 0, 0, 0);
        acc[3][0] = __builtin_amdgcn_mfma_f32_16x16x32_bf16(a3, b0, acc[3][0], 0, 0, 0);
        acc[3][1] = __builtin_amdgcn_mfma_f32_16x16x32_bf16(a3, b1, acc[3][1], 0, 0, 0);
    }

    // ---- x_t @ W_ih^T : K = 256 (fp32 -> bf16 on the fly) ----
    #pragma unroll 2
    for (int kt = 0; kt < 8; ++kt) {
        const int k0 = kt * 32 + kq * 8;
        bf16x8 av[4];
        #pragma unroll
        for (int m = 0; m < 4; ++m) {
            const float* xp = x + (size_t)(m * 16 + lr) * (S_DIM * I_DIM) + (size_t)t * I_DIM + k0;
            float4 u0 = reinterpret_cast<const float4*>(xp)[0];
            float4 u1 = reinterpret_cast<const float4*>(xp)[1];
            bf16x8 a;
            a[0] = (bf16_t)u0.x; a[1] = (bf16_t)u0.y; a[2] = (bf16_t)u0.z; a[3] = (bf16_t)u0.w;
            a[4] = (bf16_t)u1.x; a[5] = (bf16_t)u1.y; a[6] = (bf16_t)u1.z; a[7] = (bf16_t)u1.w;
            av[m] = a;
        }
        bf16x8 b0 = *reinterpret_cast<const bf16x8*>(W_ih_bf + (size_t)(colbase + lr)      * I_DIM + k0);
        bf16x8 b1 = *reinterpret_cast<const bf16x8*>(W_ih_bf + (size_t)(colbase + 16 + lr) * I_DIM + k0);
        #pragma unroll
        for (int m = 0; m < 4; ++m) {
            acc[m][0] = __builtin_amdgcn_mfma_f32_16x16x32_bf16(av[m], b0, acc[m][0], 0, 0, 0);
            acc[m][1] = __builtin_amdgcn_mfma_f32_16x16x32_bf16(av[m], b1, acc[m][1], 0, 0, 0);
        }
    }

    // ---- epilogue: bias + activation -> LDS (gate-uniform branch per wave) ----
    #pragma unroll
    for (int nt = 0; nt < 2; ++nt) {
        const int cn = colbase + nt * 16 + lr;
        const float bias = b_ih[cn] + b_hh[cn];
        #pragma unroll
        for (int m = 0; m < 4; ++m) {
            #pragma unroll
            for (int r = 0; r < 4; ++r) {
                const int row = m * 16 + kq * 4 + r;    // batch
                float v = acc[m][nt][r] + bias;
                v = (g == 2) ? tanhf(v) : sigm_(v);
                lds[g][row][nt * 16 + lr] = v;
            }
        }
    }
    __syncthreads();

    // ---- pointwise cell update: 64 rows x 32 cells, 8 per thread ----
    const int tid = threadIdx.x;
    #pragma unroll
    for (int q = 0; q < 8; ++q) {
        const int idx  = q * 256 + tid;
        const int row  = idx >> 5;        // batch
        const int cell = idx & 31;
        const int jg   = w * 32 + cell;   // global cell index
        const float iv = lds[0][row][cell];
        const float fv = lds[1][row][cell];
        const float gv = lds[2][row][cell];
        const float ov = lds[3][row][cell];
        const float cp = c_s[row * H_DIM + jg];
        const float cn = fv * cp + iv * gv;
        const float hn = ov * tanhf(cn);
        c_new_bf[row * H_DIM + jg] = (bf16_t)cn;
        h_next  [row * H_DIM + jg] = (bf16_t)hn;
        out_hidden[(size_t)row * SH + (size_t)t * H_DIM + jg] = hn;
    }
}

// ---------------------------------------------------------------------------
// Phase B (per step): stats = c_new @ G; mu = clip(stats[:, :H], 1e-6, 1e6);
// std = max(softplus(stats[:, H:]), 1e-6); c_s = mu + eps[t+1]*std.
// Grid: 8 wgs x 256 thr. wg w owns cells [w*64, w*64+64). Waves 0/1 -> mu
// columns, waves 2/3 -> std columns; combine via LDS.
// ---------------------------------------------------------------------------
__global__ __launch_bounds__(256) void k_phaseB(
    const bf16_t* __restrict__ c_new_bf, const bf16_t* __restrict__ G_T_bf,
    const float* __restrict__ eps, float* __restrict__ c_s,
    float* __restrict__ out_cmu, float* __restrict__ out_cstd, int t)
{
    __shared__ float lds[2][64][64];   // [mu/std][batch-row][cell]

    const int w    = blockIdx.x;        // 0..7
    const int v    = threadIdx.x >> 6;  // wave
    const int half = v >> 1;            // 0 = mu cols, 1 = std cols
    const int sub  = v & 1;
    const int l    = threadIdx.x & 63;
    const int lr   = l & 15;
    const int kq   = l >> 4;
    const int colbase = half * H_DIM + w * 64 + sub * 32;  // column in 1024-wide stats

    f32x4 acc[4][2];
    #pragma unroll
    for (int m = 0; m < 4; ++m) {
        acc[m][0] = (f32x4){0.f, 0.f, 0.f, 0.f};
        acc[m][1] = (f32x4){0.f, 0.f, 0.f, 0.f};
    }

    #pragma unroll 4
    for (int kt = 0; kt < 16; ++kt) {
        const int k0 = kt * 32 + kq * 8;
        bf16x8 a0 = *reinterpret_cast<const bf16x8*>(c_new_bf + (lr +  0) * H_DIM + k0);
        bf16x8 a1 = *reinterpret_cast<const bf16x8*>(c_new_bf + (lr + 16) * H_DIM + k0);
        bf16x8 a2 = *reinterpret_cast<const bf16x8*>(c_new_bf + (lr + 32) * H_DIM + k0);
        bf16x8 a3 = *reinterpret_cast<const bf16x8*>(c_new_bf + (lr + 48) * H_DIM + k0);
        bf16x8 b0 = *reinterpret_cast<const bf16x8*>(G_T_bf + (size_t)(colbase + lr)      * H_DIM + k0);
        bf16x8 b1 = *reinterpret_cast<const bf16x8*>(G_T_bf + (size_t)(colbase + 16 + lr) * H_DIM + k0);
        acc[0][0] = __builtin_amdgcn_mfma_f32_16x16x32_bf16(a0, b0, acc[0][0], 0, 0, 0);
        acc[0][1] = __builtin_amdgcn_mfma_f32_16x16x32_bf16(a0, b1, acc[0][1], 0, 0, 0);
        acc[1][0] = __builtin_amdgcn_mfma_f32_16x16x32_bf16(a1, b0, acc[1][0], 0, 0, 0);
        acc[1][1] = __builtin_amdgcn_mfma_f32_16x16x32_bf16(a1, b1, acc[1][1], 0, 0, 0);
        acc[2][0] = __builtin_amdgcn_mfma_f32_16x16x32_bf16(a2, b0, acc[2][0], 0, 0, 0);
        acc[2][1] = __builtin_amdgcn_mfma_f32_16x16x32_bf16(a2, b1, acc[2][1], 0, 0, 0);
        acc[3][0] = __builtin_amdgcn_mfma_f32_16x16x32_bf16(a3, b0, acc[3][0], 0, 0, 0);
        acc[3][1] = __builtin_amdgcn_mfma_f32_16x16x32_bf16(a3, b1, acc[3][1], 0, 0, 0);
    }

    #pragma unroll
    for (int nt = 0; nt < 2; ++nt) {
        #pragma unroll
        for (int m = 0; m < 4; ++m) {
            #pragma unroll
            for (int r = 0; r < 4; ++r) {
                const int row = m * 16 + kq * 4 + r;
                lds[half][row][sub * 32 + nt * 16 + lr] = acc[m][nt][r];
            }
        }
    }
    __syncthreads();

    const int tid = threadIdx.x;
    #pragma unroll 4
    for (int q = 0; q < 16; ++q) {
        const int idx  = q * 256 + tid;
        const int row  = idx >> 6;       // batch
        const int cell = idx & 63;
        const int jg   = w * 64 + cell;
        const float smu = lds[0][row][cell];
        const float ssd = lds[1][row][cell];
        const float mu  = fminf(fmaxf(smu, 1e-6f), 1e6f);
        const float sd  = fmaxf(softplus_(ssd), 1e-6f);
        const float e   = eps[(size_t)(t + 1) * (B_DIM * H_DIM) + row * H_DIM + jg];
        const float cs  = mu + e * sd;
        out_cmu [(size_t)row * S1H + (size_t)(t + 1) * H_DIM + jg] = mu;
        out_cstd[(size_t)row * S1H + (size_t)(t + 1) * H_DIM + jg] = sd;
        c_s[row * H_DIM + jg] = cs;
    }
}

// ---------------------------------------------------------------------------
// Final: h_f = hidden_seq[:, S-1, :], c_f = final sampled cell.
// ---------------------------------------------------------------------------
__global__ void k_final(const float* __restrict__ out_hidden, const float* __restrict__ c_s,
                        float* __restrict__ out_hf, float* __restrict__ out_cf) {
    const int i = blockIdx.x * 256 + threadIdx.x;  // b*H + j
    const int b = i >> 9, j = i & 511;
    out_hf[i] = out_hidden[(size_t)b * SH + (size_t)(S_DIM - 1) * H_DIM + j];
    out_cf[i] = c_s[i];
}

// ---------------------------------------------------------------------------
extern "C" void kernel_launch(void* const* d_in, const int* in_sizes, int n_in,
                              void* d_out, int out_size, void* d_ws, size_t ws_size,
                              hipStream_t stream) {
    (void)in_sizes; (void)n_in; (void)out_size; (void)ws_size;

    const float* x    = (const float*)d_in[0];  // (B,S,I)
    const float* eps  = (const float*)d_in[1];  // (S+1,B,H)
    const float* W_ih = (const float*)d_in[2];  // (4H,I)
    const float* W_hh = (const float*)d_in[3];  // (4H,H)
    const float* b_ih = (const float*)d_in[4];  // (4H,)
    const float* b_hh = (const float*)d_in[5];  // (4H,)
    const float* Gm   = (const float*)d_in[6];  // (H,2H)

    float* out        = (float*)d_out;
    float* out_hidden = out;                                   // (B,S,H)
    float* out_cmu    = out_hidden + (size_t)B_DIM * SH;       // (B,S+1,H)
    float* out_cstd   = out_cmu + (size_t)B_DIM * S1H;         // (B,S+1,H)
    float* out_hf     = out_cstd + (size_t)B_DIM * S1H;        // (B,H)
    float* out_cf     = out_hf + (size_t)B_DIM * H_DIM;        // (B,H)

    // workspace carve (~4.4 MB total)
    char* wsb = (char*)d_ws;
    bf16_t* W_ih_bf = (bf16_t*)(wsb);                          // 1 MB
    bf16_t* W_hh_bf = (bf16_t*)(wsb + (1u << 20));             // 2 MB
    bf16_t* G_T_bf  = (bf16_t*)(wsb + 3u * (1u << 20));        // 1 MB
    bf16_t* h_buf0  = (bf16_t*)(wsb + 4u * (1u << 20));
    bf16_t* h_buf1  = (bf16_t*)(wsb + 4u * (1u << 20) + (1u << 16));
    bf16_t* c_new   = (bf16_t*)(wsb + 4u * (1u << 20) + 2u * (1u << 16));
    float*  c_s     = (float*) (wsb + 4u * (1u << 20) + 3u * (1u << 16));

    k_convert<<<dim3(2048), dim3(256), 0, stream>>>(W_ih, W_hh, Gm, W_ih_bf, W_hh_bf, G_T_bf);
    k_init<<<dim3(128), dim3(256), 0, stream>>>(eps, h_buf0, c_s, out_cmu, out_cstd);

    bf16_t* hb[2] = {h_buf0, h_buf1};
    for (int t = 0; t < S_DIM; ++t) {
        k_phaseA<<<dim3(16), dim3(256), 0, stream>>>(hb[t & 1], x, W_hh_bf, W_ih_bf,
                                                     b_ih, b_hh, c_s,
                                                     hb[(t + 1) & 1], c_new, out_hidden, t);
        k_phaseB<<<dim3(8), dim3(256), 0, stream>>>(c_new, G_T_bf, eps, c_s,
                                                    out_cmu, out_cstd, t);
    }
    k_final<<<dim3(128), dim3(256), 0, stream>>>(out_hidden, c_s, out_hf, out_cf);
}

// Round 2
// 10571.624 us; speedup vs baseline: 3.0446x; 3.0446x over previous
//
#include <hip/hip_runtime.h>
#include <hip/hip_bf16.h>
#include <math.h>

// Problem dims (fixed by reference)
#define I_DIM 256
#define H_DIM 512
#define B_DIM 64
#define S_DIM 512
#define SH    (S_DIM * H_DIM)        // 262144
#define S1H   ((S_DIM + 1) * H_DIM)  // 262656
#define BH    (B_DIM * H_DIM)        // 32768
#define NWG   64

typedef __bf16 bf16_t;
typedef bf16_t bf16x8 __attribute__((ext_vector_type(8)));
typedef float  f32x4  __attribute__((ext_vector_type(4)));

__device__ __forceinline__ float sigm_(float x) { return 1.0f / (1.0f + __expf(-x)); }
__device__ __forceinline__ float tanh_(float x) {
    x = fminf(fmaxf(x, -15.f), 15.f);           // avoid exp overflow -> NaN
    float e = __expf(-2.f * x);
    return (1.f - e) / (1.f + e);
}
__device__ __forceinline__ float softplus_(float x) {
    return (x > 20.0f) ? x : log1pf(__expf(x));
}

// ---------------------------------------------------------------------------
// Init (every call): zero h0 buffer + barrier state; write t=0 mu/std
// (c0 = 0 -> stats = 0 exactly -> mu0 = 1e-6, std0 = ln 2).
// Grid 128 x 256 = 32768 = B*H.
// ---------------------------------------------------------------------------
__global__ void k_init(bf16_t* __restrict__ hbuf0, unsigned int* __restrict__ bar,
                       float* __restrict__ out_cmu, float* __restrict__ out_cstd) {
    const int i = blockIdx.x * 256 + threadIdx.x;   // b*H + j
    hbuf0[i] = (bf16_t)0.0f;
    const int b = i >> 9, j = i & 511;
    out_cmu [b * S1H + j] = 1e-6f;
    out_cstd[b * S1H + j] = 0.69314718055994531f;
    if (i < 32) bar[i] = 0u;
}

// ---------------------------------------------------------------------------
// Persistent kernel: 64 wgs x 256 thr. wg w owns cells [8w, 8w+8) in all
// roles: gate cols {g*512 + cell}, stat cols {cell, 512+cell}. Wave m owns
// batch rows [16m, 16m+16). All weights live in VGPRs (loaded once).
// Per step: P (gates GEMM + cell update, write c_new/h) -> grid barrier ->
// Q (stats GEMM + sampling; c_s stays in registers). ONE barrier per step.
// ---------------------------------------------------------------------------
__global__ __launch_bounds__(256, 1) void k_persist(
    const float* __restrict__ x, const float* __restrict__ eps,
    const float* __restrict__ W_ih, const float* __restrict__ W_hh,
    const float* __restrict__ b_ih, const float* __restrict__ b_hh,
    const float* __restrict__ Gm,
    bf16_t* __restrict__ hb0, bf16_t* __restrict__ hb1,
    bf16_t* __restrict__ cn0, bf16_t* __restrict__ cn1,
    unsigned int* __restrict__ bar,
    float* __restrict__ out_hidden, float* __restrict__ out_cmu,
    float* __restrict__ out_cstd, float* __restrict__ out_hf,
    float* __restrict__ out_cf)
{
    const int w  = blockIdx.x;          // cell-slice owner (0..63)
    const int wv = threadIdx.x >> 6;    // wave -> batch quarter
    const int l  = threadIdx.x & 63;
    const int lr = l & 15;              // MFMA n (B col) / m (A row)
    const int kq = l >> 4;              // k-quad
    const int nsub   = lr & 7;          // cell within slice
    const int ghalf  = lr >> 3;         // 0: i-gate/mu lane, 1: f-gate/std lane
    const int mycell = w * 8 + nsub;
    const int col0 = ghalf * H_DIM + mycell;   // i/f col in 2048-wide gate space
    const int col1 = 1024 + col0;              // g/o col
    const int gcol = ghalf * H_DIM + mycell;   // mu/std col in 1024-wide stats space
    const int row0 = wv * 16 + kq * 4;         // batch row base for C layout (+r)
    const int arow = wv * 16 + lr;             // batch row for A frags

    // ---- one-time: weights -> registers (bf16 frags), fp32 converted inline ----
    bf16x8 whh0[16], whh1[16], wih0[8], wih1[8], gfr[16];
    #pragma unroll
    for (int kt = 0; kt < 16; ++kt) {
        const float* p0 = W_hh + (size_t)col0 * H_DIM + kt * 32 + kq * 8;
        const float* p1 = W_hh + (size_t)col1 * H_DIM + kt * 32 + kq * 8;
        bf16x8 f0, f1;
        #pragma unroll
        for (int j = 0; j < 8; ++j) { f0[j] = (bf16_t)p0[j]; f1[j] = (bf16_t)p1[j]; }
        whh0[kt] = f0; whh1[kt] = f1;
    }
    #pragma unroll
    for (int kt = 0; kt < 8; ++kt) {
        const float* p0 = W_ih + (size_t)col0 * I_DIM + kt * 32 + kq * 8;
        const float* p1 = W_ih + (size_t)col1 * I_DIM + kt * 32 + kq * 8;
        bf16x8 f0, f1;
        #pragma unroll
        for (int j = 0; j < 8; ++j) { f0[j] = (bf16_t)p0[j]; f1[j] = (bf16_t)p1[j]; }
        wih0[kt] = f0; wih1[kt] = f1;
    }
    #pragma unroll
    for (int kt = 0; kt < 16; ++kt) {
        bf16x8 f;
        #pragma unroll
        for (int j = 0; j < 8; ++j)
            f[j] = (bf16_t)Gm[(size_t)(kt * 32 + kq * 8 + j) * 1024 + gcol];
        gfr[kt] = f;
    }
    const float bias0 = b_ih[col0] + b_hh[col0];
    const float bias1 = b_ih[col1] + b_hh[col1];

    // c_s(-1) = mu0 + eps[0]*std0 (wave-local carry; meaningful in ghalf==0 lanes)
    float csr[4];
    #pragma unroll
    for (int r = 0; r < 4; ++r)
        csr[r] = 1e-6f + eps[(size_t)(row0 + r) * H_DIM + mycell] * 0.69314718055994531f;

    unsigned int bk = 0;   // barrier generation

    #pragma unroll 1
    for (int t = 0; t < S_DIM; ++t) {
        const bf16_t* hin  = (t & 1) ? hb1 : hb0;
        bf16_t*       hout = (t & 1) ? hb0 : hb1;
        bf16_t*       cnb  = (t & 1) ? cn1 : cn0;

        // ================= P: gates = h @ W_hh^T + x_t @ W_ih^T =================
        f32x4 a0e = {0,0,0,0}, a0o = {0,0,0,0}, a1e = {0,0,0,0}, a1o = {0,0,0,0};
        #pragma unroll
        for (int kt = 0; kt < 16; kt += 2) {
            bf16x8 af0 = *reinterpret_cast<const bf16x8*>(hin + (size_t)arow * H_DIM + kt * 32 + kq * 8);
            bf16x8 af1 = *reinterpret_cast<const bf16x8*>(hin + (size_t)arow * H_DIM + (kt + 1) * 32 + kq * 8);
            a0e = __builtin_amdgcn_mfma_f32_16x16x32_bf16(af0, whh0[kt],     a0e, 0, 0, 0);
            a1e = __builtin_amdgcn_mfma_f32_16x16x32_bf16(af0, whh1[kt],     a1e, 0, 0, 0);
            a0o = __builtin_amdgcn_mfma_f32_16x16x32_bf16(af1, whh0[kt + 1], a0o, 0, 0, 0);
            a1o = __builtin_amdgcn_mfma_f32_16x16x32_bf16(af1, whh1[kt + 1], a1o, 0, 0, 0);
        }
        #pragma unroll
        for (int kt = 0; kt < 8; kt += 2) {
            const float* xp = x + (size_t)arow * (S_DIM * I_DIM) + (size_t)t * I_DIM + kt * 32 + kq * 8;
            float4 u0 = reinterpret_cast<const float4*>(xp)[0];
            float4 u1 = reinterpret_cast<const float4*>(xp)[1];
            float4 u2 = reinterpret_cast<const float4*>(xp + 32)[0];
            float4 u3 = reinterpret_cast<const float4*>(xp + 32)[1];
            bf16x8 af0, af1;
            af0[0]=(bf16_t)u0.x; af0[1]=(bf16_t)u0.y; af0[2]=(bf16_t)u0.z; af0[3]=(bf16_t)u0.w;
            af0[4]=(bf16_t)u1.x; af0[5]=(bf16_t)u1.y; af0[6]=(bf16_t)u1.z; af0[7]=(bf16_t)u1.w;
            af1[0]=(bf16_t)u2.x; af1[1]=(bf16_t)u2.y; af1[2]=(bf16_t)u2.z; af1[3]=(bf16_t)u2.w;
            af1[4]=(bf16_t)u3.x; af1[5]=(bf16_t)u3.y; af1[6]=(bf16_t)u3.z; af1[7]=(bf16_t)u3.w;
            a0e = __builtin_amdgcn_mfma_f32_16x16x32_bf16(af0, wih0[kt],     a0e, 0, 0, 0);
            a1e = __builtin_amdgcn_mfma_f32_16x16x32_bf16(af0, wih1[kt],     a1e, 0, 0, 0);
            a0o = __builtin_amdgcn_mfma_f32_16x16x32_bf16(af1, wih0[kt + 1], a0o, 0, 0, 0);
            a1o = __builtin_amdgcn_mfma_f32_16x16x32_bf16(af1, wih1[kt + 1], a1o, 0, 0, 0);
        }
        f32x4 a0 = a0e + a0o, a1 = a1e + a1o;

        // pointwise cell update (lane layout: col=lane&15 -> tile0: i|f, tile1: g|o)
        #pragma unroll
        for (int r = 0; r < 4; ++r) {
            float sif = sigm_(a0[r] + bias0);                       // i (ghalf 0) or f (ghalf 1)
            float v1  = a1[r] + bias1;
            float go  = (ghalf == 0) ? tanh_(v1) : sigm_(v1);       // g or o
            float fv  = __shfl_xor(sif, 8);
            float ov  = __shfl_xor(go, 8);
            float cn  = fv * csr[r] + sif * go;
            float hn  = ov * tanh_(cn);
            if (ghalf == 0) {
                const int row = row0 + r;
                cnb [(size_t)row * H_DIM + mycell] = (bf16_t)cn;
                hout[(size_t)row * H_DIM + mycell] = (bf16_t)hn;
                out_hidden[(size_t)row * SH + (size_t)t * H_DIM + mycell] = hn;
                if (t == S_DIM - 1) out_hf[row * H_DIM + mycell] = hn;
            }
        }

        // ================= grid barrier (c_new/h now globally visible) ==========
        __syncthreads();
        ++bk;
        if (threadIdx.x == 0) {
            __builtin_amdgcn_fence(__ATOMIC_RELEASE, "agent");      // wb dirty L2 -> IC
            unsigned int old = __hip_atomic_fetch_add(&bar[0], 1u, __ATOMIC_RELAXED,
                                                      __HIP_MEMORY_SCOPE_AGENT);
            if (old == bk * NWG - 1) {
                __builtin_amdgcn_fence(__ATOMIC_ACQUIRE, "agent");  // transitivity
                __hip_atomic_store(&bar[16], bk, __ATOMIC_RELEASE,
                                   __HIP_MEMORY_SCOPE_AGENT);
            }
        }
        while (__hip_atomic_load(&bar[16], __ATOMIC_RELAXED, __HIP_MEMORY_SCOPE_AGENT) < bk)
            __builtin_amdgcn_s_sleep(2);
        __builtin_amdgcn_fence(__ATOMIC_ACQUIRE, "agent");          // inv stale L1/L2

        // ================= Q: stats = c_new @ G; sample =========================
        f32x4 se = {0,0,0,0}, so = {0,0,0,0};
        #pragma unroll
        for (int kt = 0; kt < 16; kt += 2) {
            bf16x8 af0 = *reinterpret_cast<const bf16x8*>(cnb + (size_t)arow * H_DIM + kt * 32 + kq * 8);
            bf16x8 af1 = *reinterpret_cast<const bf16x8*>(cnb + (size_t)arow * H_DIM + (kt + 1) * 32 + kq * 8);
            se = __builtin_amdgcn_mfma_f32_16x16x32_bf16(af0, gfr[kt],     se, 0, 0, 0);
            so = __builtin_amdgcn_mfma_f32_16x16x32_bf16(af1, gfr[kt + 1], so, 0, 0, 0);
        }
        f32x4 st = se + so;
        #pragma unroll
        for (int r = 0; r < 4; ++r) {
            const int row = row0 + r;
            float sv  = st[r];
            float muv = fminf(fmaxf(sv, 1e-6f), 1e6f);
            float sdv = fmaxf(softplus_(sv), 1e-6f);
            float outv = (ghalf == 0) ? muv : sdv;
            float* outp = ((ghalf == 0) ? out_cmu : out_cstd)
                          + (size_t)row * S1H + (size_t)(t + 1) * H_DIM + mycell;
            *outp = outv;
            float sd_p = __shfl_xor(outv, 8);   // ghalf==0 lanes receive partner's std
            float ev = eps[(size_t)(t + 1) * BH + (size_t)row * H_DIM + mycell];
            csr[r] = muv + ev * sd_p;           // carry c_s in registers
            if (t == S_DIM - 1 && ghalf == 0) out_cf[row * H_DIM + mycell] = csr[r];
        }
        // no barrier here: P(t+1) needs only h (visible since B(t)) and local csr
    }
}

// ---------------------------------------------------------------------------
extern "C" void kernel_launch(void* const* d_in, const int* in_sizes, int n_in,
                              void* d_out, int out_size, void* d_ws, size_t ws_size,
                              hipStream_t stream) {
    (void)in_sizes; (void)n_in; (void)out_size; (void)ws_size;

    const float* x    = (const float*)d_in[0];  // (B,S,I)
    const float* eps  = (const float*)d_in[1];  // (S+1,B,H)
    const float* W_ih = (const float*)d_in[2];  // (4H,I)
    const float* W_hh = (const float*)d_in[3];  // (4H,H)
    const float* b_ih = (const float*)d_in[4];  // (4H,)
    const float* b_hh = (const float*)d_in[5];  // (4H,)
    const float* Gm   = (const float*)d_in[6];  // (H,2H)

    float* out        = (float*)d_out;
    float* out_hidden = out;                                   // (B,S,H)
    float* out_cmu    = out_hidden + (size_t)B_DIM * SH;       // (B,S+1,H)
    float* out_cstd   = out_cmu + (size_t)B_DIM * S1H;         // (B,S+1,H)
    float* out_hf     = out_cstd + (size_t)B_DIM * S1H;        // (B,H)
    float* out_cf     = out_hf + (size_t)B_DIM * H_DIM;        // (B,H)

    // workspace carve (~260 KB)
    char* wsb = (char*)d_ws;
    bf16_t* hb0 = (bf16_t*)(wsb);                     // 64 KB  h double-buffer
    bf16_t* hb1 = (bf16_t*)(wsb + (1u << 16));        // 64 KB
    bf16_t* cn0 = (bf16_t*)(wsb + 2u * (1u << 16));   // 64 KB  c_new double-buffer
    bf16_t* cn1 = (bf16_t*)(wsb + 3u * (1u << 16));   // 64 KB
    unsigned int* bar = (unsigned int*)(wsb + 4u * (1u << 16)); // barrier state

    k_init<<<dim3(128), dim3(256), 0, stream>>>(hb0, bar, out_cmu, out_cstd);
    k_persist<<<dim3(NWG), dim3(256), 0, stream>>>(
        x, eps, W_ih, W_hh, b_ih, b_hh, Gm,
        hb0, hb1, cn0, cn1, bar,
        out_hidden, out_cmu, out_cstd, out_hf, out_cf);
}

// Round 3
// 8371.001 us; speedup vs baseline: 3.8450x; 1.2629x over previous
//
#include <hip/hip_runtime.h>
#include <hip/hip_bf16.h>
#include <math.h>

// Problem dims (fixed by reference)
#define I_DIM 256
#define H_DIM 512
#define B_DIM 64
#define S_DIM 512
#define SH    (S_DIM * H_DIM)        // 262144
#define S1H   ((S_DIM + 1) * H_DIM)  // 262656
#define BH    (B_DIM * H_DIM)        // 32768
#define NWG   64

typedef __bf16 bf16_t;
typedef bf16_t bf16x8 __attribute__((ext_vector_type(8)));
typedef float  f32x4  __attribute__((ext_vector_type(4)));

__device__ __forceinline__ float sigm_(float x) { return 1.0f / (1.0f + __expf(-x)); }
__device__ __forceinline__ float tanh_(float x) {
    x = fminf(fmaxf(x, -15.f), 15.f);           // avoid exp overflow -> NaN
    float e = __expf(-2.f * x);
    return (1.f - e) / (1.f + e);
}
__device__ __forceinline__ float softplus_(float x) {
    return (x > 20.0f) ? x : log1pf(__expf(x));
}
__device__ __forceinline__ unsigned short bfbits_(float f) {
    return __builtin_bit_cast(unsigned short, (bf16_t)f);
}

// Cache-bypassing (coherence-point) 16B fragment load: two relaxed agent-scope
// b64 atomic loads -> global_load_dwordx2 with sc0/sc1 bits, NO buffer_inv.
__device__ __forceinline__ bf16x8 ld_frag_agent(const bf16_t* base, int elem_idx) {
    const unsigned long long* p = (const unsigned long long*)(base) + (elem_idx >> 2);
    unsigned long long lo = __hip_atomic_load(p,     __ATOMIC_RELAXED, __HIP_MEMORY_SCOPE_AGENT);
    unsigned long long hi = __hip_atomic_load(p + 1, __ATOMIC_RELAXED, __HIP_MEMORY_SCOPE_AGENT);
    union { unsigned long long q[2]; bf16x8 v; } u;
    u.q[0] = lo; u.q[1] = hi;
    return u.v;
}

// ---------------------------------------------------------------------------
// Init (every call): zero h0 buffer + barrier state; write t=0 mu/std
// (c0 = 0 -> stats = 0 exactly -> mu0 = 1e-6, std0 = ln 2).
// ---------------------------------------------------------------------------
__global__ void k_init(bf16_t* __restrict__ hbuf0, unsigned int* __restrict__ bar,
                       float* __restrict__ out_cmu, float* __restrict__ out_cstd) {
    const int i = blockIdx.x * 256 + threadIdx.x;   // b*H + j
    hbuf0[i] = (bf16_t)0.0f;
    const int b = i >> 9, j = i & 511;
    out_cmu [b * S1H + j] = 1e-6f;
    out_cstd[b * S1H + j] = 0.69314718055994531f;
    if (i < 32) bar[i] = 0u;
}

// ---------------------------------------------------------------------------
// Persistent kernel: 64 wgs x 256 thr. wg w owns cells [8w, 8w+8) in all
// roles; wave wv owns batch rows [16wv, 16wv+16). Weights live in registers
// (loaded once). Per step: P (gates GEMM + cell update; h/c exchanged via
// relaxed agent-scope atomics) -> counter barrier (no cache-wide ops) ->
// Q (stats GEMM + sampling; c_s carried in registers).
// ---------------------------------------------------------------------------
__global__ __launch_bounds__(256, 1) void k_persist(
    const float* __restrict__ x, const float* __restrict__ eps,
    const float* __restrict__ W_ih, const float* __restrict__ W_hh,
    const float* __restrict__ b_ih, const float* __restrict__ b_hh,
    const float* __restrict__ Gm,
    bf16_t* __restrict__ hb0, bf16_t* __restrict__ hb1,
    bf16_t* __restrict__ cn0, bf16_t* __restrict__ cn1,
    unsigned int* __restrict__ bar,
    float* __restrict__ out_hidden, float* __restrict__ out_cmu,
    float* __restrict__ out_cstd, float* __restrict__ out_hf,
    float* __restrict__ out_cf)
{
    const int w  = blockIdx.x;          // cell-slice owner (0..63)
    const int wv = threadIdx.x >> 6;    // wave -> batch quarter
    const int l  = threadIdx.x & 63;
    const int lr = l & 15;              // MFMA n (B col) / m (A row)
    const int kq = l >> 4;              // k-quad
    const int nsub   = lr & 7;          // cell within slice
    const int ghalf  = lr >> 3;         // 0: i-gate/mu lane, 1: f-gate/std lane
    const int mycell = w * 8 + nsub;
    const int col0 = ghalf * H_DIM + mycell;   // i/f col in 2048-wide gate space
    const int col1 = 1024 + col0;              // g/o col
    const int gcol = ghalf * H_DIM + mycell;   // mu/std col in 1024-wide stats
    const int row0 = wv * 16 + kq * 4;         // batch row base for C layout (+r)
    const int arow = wv * 16 + lr;             // batch row for A frags

    // ---- one-time: weights -> registers (bf16 frags), fp32 converted inline ----
    bf16x8 whh0[16], whh1[16], wih0[8], wih1[8], gfr[16];
    #pragma unroll
    for (int kt = 0; kt < 16; ++kt) {
        const float* p0 = W_hh + (size_t)col0 * H_DIM + kt * 32 + kq * 8;
        const float* p1 = W_hh + (size_t)col1 * H_DIM + kt * 32 + kq * 8;
        bf16x8 f0, f1;
        #pragma unroll
        for (int j = 0; j < 8; ++j) { f0[j] = (bf16_t)p0[j]; f1[j] = (bf16_t)p1[j]; }
        whh0[kt] = f0; whh1[kt] = f1;
    }
    #pragma unroll
    for (int kt = 0; kt < 8; ++kt) {
        const float* p0 = W_ih + (size_t)col0 * I_DIM + kt * 32 + kq * 8;
        const float* p1 = W_ih + (size_t)col1 * I_DIM + kt * 32 + kq * 8;
        bf16x8 f0, f1;
        #pragma unroll
        for (int j = 0; j < 8; ++j) { f0[j] = (bf16_t)p0[j]; f1[j] = (bf16_t)p1[j]; }
        wih0[kt] = f0; wih1[kt] = f1;
    }
    #pragma unroll
    for (int kt = 0; kt < 16; ++kt) {
        bf16x8 f;
        #pragma unroll
        for (int j = 0; j < 8; ++j)
            f[j] = (bf16_t)Gm[(size_t)(kt * 32 + kq * 8 + j) * 1024 + gcol];
        gfr[kt] = f;
    }
    const float bias0 = b_ih[col0] + b_hh[col0];
    const float bias1 = b_ih[col1] + b_hh[col1];

    // c_s(-1) = mu0 + eps[0]*std0 (register carry; meaningful in ghalf==0 lanes)
    float csr[4];
    #pragma unroll
    for (int r = 0; r < 4; ++r)
        csr[r] = 1e-6f + eps[(size_t)(row0 + r) * H_DIM + mycell] * 0.69314718055994531f;

    unsigned int* hout_u32;
    unsigned int* cnb_u32;

    #pragma unroll 1
    for (int t = 0; t < S_DIM; ++t) {
        const bf16_t* hin  = (t & 1) ? hb1 : hb0;
        bf16_t*       hout = (t & 1) ? hb0 : hb1;
        bf16_t*       cnb  = (t & 1) ? cn1 : cn0;
        hout_u32 = (unsigned int*)hout;
        cnb_u32  = (unsigned int*)cnb;

        // ============ P: gates = h @ W_hh^T + x_t @ W_ih^T (h via agent loads) ==
        f32x4 a0e = {0,0,0,0}, a0o = {0,0,0,0}, a1e = {0,0,0,0}, a1o = {0,0,0,0};
        #pragma unroll
        for (int kt = 0; kt < 16; kt += 2) {
            bf16x8 af0 = ld_frag_agent(hin, arow * H_DIM + kt * 32 + kq * 8);
            bf16x8 af1 = ld_frag_agent(hin, arow * H_DIM + (kt + 1) * 32 + kq * 8);
            a0e = __builtin_amdgcn_mfma_f32_16x16x32_bf16(af0, whh0[kt],     a0e, 0, 0, 0);
            a1e = __builtin_amdgcn_mfma_f32_16x16x32_bf16(af0, whh1[kt],     a1e, 0, 0, 0);
            a0o = __builtin_amdgcn_mfma_f32_16x16x32_bf16(af1, whh0[kt + 1], a0o, 0, 0, 0);
            a1o = __builtin_amdgcn_mfma_f32_16x16x32_bf16(af1, whh1[kt + 1], a1o, 0, 0, 0);
        }
        #pragma unroll
        for (int kt = 0; kt < 8; kt += 2) {
            const float* xp = x + (size_t)arow * (S_DIM * I_DIM) + (size_t)t * I_DIM + kt * 32 + kq * 8;
            float4 u0 = reinterpret_cast<const float4*>(xp)[0];
            float4 u1 = reinterpret_cast<const float4*>(xp)[1];
            float4 u2 = reinterpret_cast<const float4*>(xp + 32)[0];
            float4 u3 = reinterpret_cast<const float4*>(xp + 32)[1];
            bf16x8 af0, af1;
            af0[0]=(bf16_t)u0.x; af0[1]=(bf16_t)u0.y; af0[2]=(bf16_t)u0.z; af0[3]=(bf16_t)u0.w;
            af0[4]=(bf16_t)u1.x; af0[5]=(bf16_t)u1.y; af0[6]=(bf16_t)u1.z; af0[7]=(bf16_t)u1.w;
            af1[0]=(bf16_t)u2.x; af1[1]=(bf16_t)u2.y; af1[2]=(bf16_t)u2.z; af1[3]=(bf16_t)u2.w;
            af1[4]=(bf16_t)u3.x; af1[5]=(bf16_t)u3.y; af1[6]=(bf16_t)u3.z; af1[7]=(bf16_t)u3.w;
            a0e = __builtin_amdgcn_mfma_f32_16x16x32_bf16(af0, wih0[kt],     a0e, 0, 0, 0);
            a1e = __builtin_amdgcn_mfma_f32_16x16x32_bf16(af0, wih1[kt],     a1e, 0, 0, 0);
            a0o = __builtin_amdgcn_mfma_f32_16x16x32_bf16(af1, wih0[kt + 1], a0o, 0, 0, 0);
            a1o = __builtin_amdgcn_mfma_f32_16x16x32_bf16(af1, wih1[kt + 1], a1o, 0, 0, 0);
        }
        f32x4 a0 = a0e + a0o, a1 = a1e + a1o;

        // ---- pointwise cell update; h/c written via relaxed agent stores -------
        #pragma unroll
        for (int r = 0; r < 4; ++r) {
            float sif = sigm_(a0[r] + bias0);                       // i or f
            float v1  = a1[r] + bias1;
            float go  = (ghalf == 0) ? tanh_(v1) : sigm_(v1);       // g or o
            float fv  = __shfl_xor(sif, 8);
            float ov  = __shfl_xor(go, 8);
            float cn  = fv * csr[r] + sif * go;
            float hn  = ov * tanh_(cn);
            unsigned hcw = ((unsigned)bfbits_(cn) << 16) | (unsigned)bfbits_(hn);
            unsigned pp  = __shfl_xor(hcw, 1);                      // partner cell
            float    hp  = __shfl_xor(hn, 1);
            if (ghalf == 0 && !(lr & 1)) {
                const int row  = row0 + r;
                const int cidx = (row * H_DIM + mycell) >> 1;       // u32 index
                unsigned hw = ((pp & 0xFFFFu) << 16) | (hcw & 0xFFFFu);
                unsigned cw = (pp & 0xFFFF0000u)     | (hcw >> 16);
                __hip_atomic_store(hout_u32 + cidx, hw, __ATOMIC_RELAXED, __HIP_MEMORY_SCOPE_AGENT);
                __hip_atomic_store(cnb_u32  + cidx, cw, __ATOMIC_RELAXED, __HIP_MEMORY_SCOPE_AGENT);
                float2 hv; hv.x = hn; hv.y = hp;
                *(float2*)(out_hidden + (size_t)row * SH + (size_t)t * H_DIM + mycell) = hv;
                if (t == S_DIM - 1)
                    *(float2*)(out_hf + row * H_DIM + mycell) = hv;
            }
        }

        // ============ barrier: monotone counter, zero cache-wide ops ============
        __threadfence_block();            // vmcnt drain (stores at coherence pt)
        __syncthreads();
        if (threadIdx.x == 0) {
            const unsigned target = (unsigned)(t + 1) * NWG;
            __hip_atomic_fetch_add(&bar[0], 1u, __ATOMIC_RELAXED, __HIP_MEMORY_SCOPE_AGENT);
            while (__hip_atomic_load(&bar[0], __ATOMIC_RELAXED, __HIP_MEMORY_SCOPE_AGENT) < target)
                __builtin_amdgcn_s_sleep(1);
        }
        __syncthreads();
        __atomic_signal_fence(__ATOMIC_ACQUIRE);   // compiler-only ordering

        // ============ Q: stats = c_new @ G (c via agent loads); sample ==========
        f32x4 se = {0,0,0,0}, so = {0,0,0,0};
        #pragma unroll
        for (int kt = 0; kt < 16; kt += 2) {
            bf16x8 af0 = ld_frag_agent(cnb, arow * H_DIM + kt * 32 + kq * 8);
            bf16x8 af1 = ld_frag_agent(cnb, arow * H_DIM + (kt + 1) * 32 + kq * 8);
            se = __builtin_amdgcn_mfma_f32_16x16x32_bf16(af0, gfr[kt],     se, 0, 0, 0);
            so = __builtin_amdgcn_mfma_f32_16x16x32_bf16(af1, gfr[kt + 1], so, 0, 0, 0);
        }
        f32x4 st = se + so;
        #pragma unroll
        for (int r = 0; r < 4; ++r) {
            const int row = row0 + r;
            float sv  = st[r];
            float muv = fminf(fmaxf(sv, 1e-6f), 1e6f);
            float sdv = fmaxf(softplus_(sv), 1e-6f);
            float outv = (ghalf == 0) ? muv : sdv;
            float op   = __shfl_xor(outv, 1);       // partner cell's value
            if (!(lr & 1)) {
                float* outp = ((ghalf == 0) ? out_cmu : out_cstd)
                              + (size_t)row * S1H + (size_t)(t + 1) * H_DIM + mycell;
                float2 v2; v2.x = outv; v2.y = op;
                *(float2*)outp = v2;
            }
            float sd_p = __shfl_xor(outv, 8);       // ghalf==0 gets partner's std
            float ev = eps[(size_t)(t + 1) * BH + (size_t)row * H_DIM + mycell];
            csr[r] = muv + ev * sd_p;               // register carry of c_s
            if (t == S_DIM - 1 && ghalf == 0) out_cf[row * H_DIM + mycell] = csr[r];
        }
        // no second barrier: P(t+1) reads only h(t) (visible) and local csr
    }
}

// ---------------------------------------------------------------------------
extern "C" void kernel_launch(void* const* d_in, const int* in_sizes, int n_in,
                              void* d_out, int out_size, void* d_ws, size_t ws_size,
                              hipStream_t stream) {
    (void)in_sizes; (void)n_in; (void)out_size; (void)ws_size;

    const float* x    = (const float*)d_in[0];  // (B,S,I)
    const float* eps  = (const float*)d_in[1];  // (S+1,B,H)
    const float* W_ih = (const float*)d_in[2];  // (4H,I)
    const float* W_hh = (const float*)d_in[3];  // (4H,H)
    const float* b_ih = (const float*)d_in[4];  // (4H,)
    const float* b_hh = (const float*)d_in[5];  // (4H,)
    const float* Gm   = (const float*)d_in[6];  // (H,2H)

    float* out        = (float*)d_out;
    float* out_hidden = out;                                   // (B,S,H)
    float* out_cmu    = out_hidden + (size_t)B_DIM * SH;       // (B,S+1,H)
    float* out_cstd   = out_cmu + (size_t)B_DIM * S1H;         // (B,S+1,H)
    float* out_hf     = out_cstd + (size_t)B_DIM * S1H;        // (B,H)
    float* out_cf     = out_hf + (size_t)B_DIM * H_DIM;        // (B,H)

    // workspace carve (~260 KB)
    char* wsb = (char*)d_ws;
    bf16_t* hb0 = (bf16_t*)(wsb);                     // 64 KB  h double-buffer
    bf16_t* hb1 = (bf16_t*)(wsb + (1u << 16));        // 64 KB
    bf16_t* cn0 = (bf16_t*)(wsb + 2u * (1u << 16));   // 64 KB  c_new double-buffer
    bf16_t* cn1 = (bf16_t*)(wsb + 3u * (1u << 16));   // 64 KB
    unsigned int* bar = (unsigned int*)(wsb + 4u * (1u << 16)); // barrier state

    k_init<<<dim3(128), dim3(256), 0, stream>>>(hb0, bar, out_cmu, out_cstd);
    k_persist<<<dim3(NWG), dim3(256), 0, stream>>>(
        x, eps, W_ih, W_hh, b_ih, b_hh, Gm,
        hb0, hb1, cn0, cn1, bar,
        out_hidden, out_cmu, out_cstd, out_hf, out_cf);
}